// Round 1
// baseline (6779.769 us; speedup 1.0000x reference)
//
#include <hip/hip_runtime.h>
#include <math.h>

#define B  128
#define L  196
#define F2 512
#define T  32
#define D  256
#define H  512
#define H4 2048
#define KCAT 1280   // 512 (context) + 512 (h) + 256 (word)

__device__ __forceinline__ float sigf(float x) { return 1.0f / (1.0f + expf(-x)); }

// features_mean[b,f] = mean_l X[b,l,f]
__global__ void k_mean(const float* __restrict__ X, float* __restrict__ fm) {
    int b = blockIdx.x;
    for (int f = threadIdx.x; f < F2; f += 256) {
        const float* xb = X + (size_t)b * L * F2 + f;
        float s = 0.f;
        for (int l = 0; l < L; ++l) s += xb[(size_t)l * F2];
        fm[b * F2 + f] = s * (1.0f / L);
    }
}

// feat_score[b,l] = X[b,l,:] . w_a + b_a   (one wave per row)
__global__ void k_fscore(const float* __restrict__ X, const float* __restrict__ w_a,
                         const float* __restrict__ b_a, float* __restrict__ fs) {
    int row = blockIdx.x * 4 + (threadIdx.x >> 6);
    int lane = threadIdx.x & 63;
    if (row >= B * L) return;
    const float* xr = X + (size_t)row * F2;
    float s = 0.f;
    for (int f = lane; f < F2; f += 64) s += xr[f] * w_a[f];
    for (int off = 32; off > 0; off >>= 1) s += __shfl_down(s, off);
    if (lane == 0) fs[row] = s + b_a[0];
}

// h0 = tanh(fm @ w_h + b_h) -> xh0 h-slot ; c0 = tanh(fm @ w_c + b_c) -> c
__global__ void k_init(const float* __restrict__ fm,
                       const float* __restrict__ w_h, const float* __restrict__ b_h,
                       const float* __restrict__ w_c, const float* __restrict__ b_c,
                       float* __restrict__ xh0, float* __restrict__ c) {
    __shared__ float a[F2];
    int b = blockIdx.x;
    for (int k = threadIdx.x; k < F2; k += 256) a[k] = fm[b * F2 + k];
    __syncthreads();
    int n = blockIdx.y * 256 + threadIdx.x;   // 0..511
    float sh = 0.f, sc = 0.f;
    for (int k = 0; k < F2; ++k) {
        float av = a[k];
        sh += av * w_h[(size_t)k * H + n];
        sc += av * w_c[(size_t)k * H + n];
    }
    xh0[(size_t)b * 1024 + 512 + n] = tanhf(sh + b_h[n]);
    c[(size_t)b * H + n]            = tanhf(sc + b_c[n]);
}

// attention + softmax + context chunk. grid (B, 4), 256 threads.
// reads h from xh[b][512..1023], writes ctx to xh[b][fc*128 .. fc*128+127]
__global__ void k_attn(const float* __restrict__ X, const float* __restrict__ fscore,
                       const float* __restrict__ w_a_h, float* __restrict__ xh,
                       float* __restrict__ out_a, int t) {
    __shared__ float sred[256];
    __shared__ float sal[256];
    __shared__ float spart[2][128];
    int b = blockIdx.x, fc = blockIdx.y, tid = threadIdx.x;

    // hscore = h[b] . w_a_h
    const float* hb = xh + (size_t)b * 1024 + 512;
    float p = hb[tid] * w_a_h[tid] + hb[tid + 256] * w_a_h[tid + 256];
    sred[tid] = p; __syncthreads();
    for (int s = 128; s > 0; s >>= 1) { if (tid < s) sred[tid] += sred[tid + s]; __syncthreads(); }
    float hs = sred[0];
    __syncthreads();

    // score + softmax over L
    float scv = 0.f;
    if (tid < L) scv = tanhf(hs + fscore[b * L + tid]);
    sred[tid] = (tid < L) ? scv : -3.0e38f;
    __syncthreads();
    for (int s = 128; s > 0; s >>= 1) { if (tid < s) sred[tid] = fmaxf(sred[tid], sred[tid + s]); __syncthreads(); }
    float mx = sred[0];
    __syncthreads();
    float ex = (tid < L) ? expf(scv - mx) : 0.f;
    sred[tid] = ex; __syncthreads();
    for (int s = 128; s > 0; s >>= 1) { if (tid < s) sred[tid] += sred[tid + s]; __syncthreads(); }
    float al = ex / sred[0];
    if (tid < L) sal[tid] = al;
    if (fc == 0 && tid < L) out_a[((size_t)b * T + t) * L + tid] = al;
    __syncthreads();

    // context chunk: f = fc*128 + (tid&127), split L across two half-groups
    int half = tid >> 7, fi = tid & 127;
    int f = fc * 128 + fi;
    const float* xp = X + (size_t)b * L * F2 + f;
    float acc = 0.f;
    int l0 = half * 98;
    for (int l = l0; l < l0 + 98; ++l) acc += xp[(size_t)l * F2] * sal[l];
    spart[half][fi] = acc;
    __syncthreads();
    if (tid < 128) xh[(size_t)b * 1024 + fc * 128 + tid] = spart[0][tid] + spart[1][tid];
}

// gates GEMM (M=128, N=4 gates x 512, K=1280) + fused LSTM cell.
// grid (32 n-tiles of 16, 4 row-tiles of 32), 256 threads.
// A rows: [ctx(512) | h(512)] from xh_cur, word(256) fetched directly.
// Wcat rows: [K_bot(512); R(512); K_top(256)]. N tiled gate-interleaved so each
// block owns all 4 gates for its 16 n values -> cell fused in epilogue.
__global__ void k_gates(const float* __restrict__ A, const float* __restrict__ word,
                        const float* __restrict__ Wcat, const float* __restrict__ bias,
                        float* __restrict__ xh_next, float* __restrict__ c,
                        float* __restrict__ hiddens, float* __restrict__ memory, int t) {
    __shared__ float As[16][33];
    __shared__ float Bs[16][65];
    __shared__ float Zs[32][65];
    int tid = threadIdx.x;
    int tr = tid >> 4;     // 0..15 -> rows tr*2, tr*2+1
    int tc = tid & 15;     // cols tc*4 .. tc*4+3
    int rowBase = blockIdx.y * 32;
    int nBase = blockIdx.x * 16;
    float acc[2][4] = {{0.f,0.f,0.f,0.f},{0.f,0.f,0.f,0.f}};

    for (int k0 = 0; k0 < KCAT; k0 += 16) {
        for (int i = tid; i < 32 * 16; i += 256) {
            int r = i >> 4, kk = i & 15;
            int k = k0 + kk;
            float v;
            if (k < 1024) v = A[(size_t)(rowBase + r) * 1024 + k];
            else          v = word[((size_t)(rowBase + r) * T + t) * D + (k - 1024)];
            As[kk][r] = v;
        }
        for (int i = tid; i < 16 * 64; i += 256) {
            int kk = i >> 6, cc = i & 63;
            int col = (cc >> 4) * H + nBase + (cc & 15);
            Bs[kk][cc] = Wcat[(size_t)(k0 + kk) * H4 + col];
        }
        __syncthreads();
        #pragma unroll
        for (int kk = 0; kk < 16; ++kk) {
            float av0 = As[kk][tr * 2], av1 = As[kk][tr * 2 + 1];
            float bv0 = Bs[kk][tc * 4], bv1 = Bs[kk][tc * 4 + 1];
            float bv2 = Bs[kk][tc * 4 + 2], bv3 = Bs[kk][tc * 4 + 3];
            acc[0][0] += av0 * bv0; acc[0][1] += av0 * bv1; acc[0][2] += av0 * bv2; acc[0][3] += av0 * bv3;
            acc[1][0] += av1 * bv0; acc[1][1] += av1 * bv1; acc[1][2] += av1 * bv2; acc[1][3] += av1 * bv3;
        }
        __syncthreads();
    }

    // z tile (+bias) to LDS
    #pragma unroll
    for (int m = 0; m < 2; ++m)
        #pragma unroll
        for (int n = 0; n < 4; ++n) {
            int r = tr * 2 + m, cc = tc * 4 + n;
            int col = (cc >> 4) * H + nBase + (cc & 15);
            Zs[r][cc] = acc[m][n] + bias[col];
        }
    __syncthreads();

    // fused LSTM cell: 32 rows x 16 n, 2 per thread
    for (int i = tid; i < 32 * 16; i += 256) {
        int r = i >> 4, nn = i & 15;
        int b = rowBase + r, n = nBase + nn;
        float zi = Zs[r][nn], zf = Zs[r][16 + nn], zg = Zs[r][32 + nn], zo = Zs[r][48 + nn];
        float cv = c[(size_t)b * H + n];
        float cn = sigf(zf) * cv + sigf(zi) * tanhf(zg);
        float hn = sigf(zo) * tanhf(cn);
        c[(size_t)b * H + n] = cn;
        xh_next[(size_t)b * 1024 + 512 + n] = hn;
        hiddens[((size_t)b * T + t) * H + n] = hn;
        memory[((size_t)t * B + b) * H + n] = cn;
    }
}

extern "C" void kernel_launch(void* const* d_in, const int* in_sizes, int n_in,
                              void* d_out, int out_size, void* d_ws, size_t ws_size,
                              hipStream_t stream) {
    (void)in_sizes; (void)n_in; (void)out_size; (void)ws_size;
    const float* X      = (const float*)d_in[0];
    const float* word   = (const float*)d_in[1];
    const float* w_h    = (const float*)d_in[2];
    const float* b_h    = (const float*)d_in[3];
    const float* w_c    = (const float*)d_in[4];
    const float* b_c    = (const float*)d_in[5];
    const float* w_a_h  = (const float*)d_in[6];
    const float* w_a    = (const float*)d_in[7];
    const float* b_a    = (const float*)d_in[8];
    const float* k_w    = (const float*)d_in[9];   // [768, 2048]
    const float* r_w    = (const float*)d_in[10];  // [512, 2048]
    const float* bias   = (const float*)d_in[11];  // [2048]

    float* out_h = (float*)d_out;                        // [B,T,H]
    float* out_m = out_h + (size_t)B * T * H;            // [T,B,H]
    float* out_a = out_m + (size_t)T * B * H;            // [B,T,L]

    // workspace layout (floats): Wcat[1280*2048] fm[B*F2] fscore[B*L] c[B*H] xh0[B*1024] xh1[B*1024]
    float* ws     = (float*)d_ws;
    float* Wcat   = ws;
    float* fm     = Wcat + (size_t)KCAT * H4;
    float* fscore = fm + (size_t)B * F2;
    float* cbuf   = fscore + (size_t)B * L;
    float* xh0    = cbuf + (size_t)B * H;
    float* xh1    = xh0 + (size_t)B * 1024;

    // Wcat = [kernel rows 256..767 (context) ; recurrent ; kernel rows 0..255 (word)]
    hipMemcpyAsync(Wcat,                       k_w + (size_t)D * H4, (size_t)F2 * H4 * sizeof(float), hipMemcpyDeviceToDevice, stream);
    hipMemcpyAsync(Wcat + (size_t)F2 * H4,     r_w,                  (size_t)H  * H4 * sizeof(float), hipMemcpyDeviceToDevice, stream);
    hipMemcpyAsync(Wcat + (size_t)(F2+H) * H4, k_w,                  (size_t)D  * H4 * sizeof(float), hipMemcpyDeviceToDevice, stream);

    k_mean<<<B, 256, 0, stream>>>(X, fm);
    k_fscore<<<(B * L) / 4, 256, 0, stream>>>(X, w_a, b_a, fscore);
    k_init<<<dim3(B, 2), 256, 0, stream>>>(fm, w_h, b_h, w_c, b_c, xh0, cbuf);

    for (int t = 0; t < T; ++t) {
        float* cur = (t & 1) ? xh1 : xh0;
        float* nxt = (t & 1) ? xh0 : xh1;
        k_attn<<<dim3(B, 4), 256, 0, stream>>>(X, fscore, w_a_h, cur, out_a, t);
        k_gates<<<dim3(32, 4), 256, 0, stream>>>(cur, word, Wcat, bias, nxt, cbuf, out_h, out_m, t);
    }
}

// Round 2
// 974.171 us; speedup vs baseline: 6.9595x; 6.9595x over previous
//
#include <hip/hip_runtime.h>
#include <math.h>

#define B  128
#define L  196
#define F2 512
#define T  32
#define D  256
#define H  512
#define H4 2048
#define KCAT 1280   // 512 (context) + 512 (h) + 256 (word)
#define KS 8
#define KCHUNK 160  // KCAT / KS
#define BK 32

__device__ __forceinline__ float sigf(float x) { return 1.0f / (1.0f + expf(-x)); }

// features_mean[b,f] = mean_l X[b,l,f]
__global__ void k_mean(const float* __restrict__ X, float* __restrict__ fm) {
    int b = blockIdx.x;
    for (int f = threadIdx.x; f < F2; f += 256) {
        const float* xb = X + (size_t)b * L * F2 + f;
        float s = 0.f;
        for (int l = 0; l < L; ++l) s += xb[(size_t)l * F2];
        fm[b * F2 + f] = s * (1.0f / L);
    }
}

// feat_score[b,l] = X[b,l,:] . w_a + b_a   (one wave per row)
__global__ void k_fscore(const float* __restrict__ X, const float* __restrict__ w_a,
                         const float* __restrict__ b_a, float* __restrict__ fs) {
    int row = blockIdx.x * 4 + (threadIdx.x >> 6);
    int lane = threadIdx.x & 63;
    if (row >= B * L) return;
    const float* xr = X + (size_t)row * F2;
    float s = 0.f;
    for (int f = lane; f < F2; f += 64) s += xr[f] * w_a[f];
    for (int off = 32; off > 0; off >>= 1) s += __shfl_down(s, off);
    if (lane == 0) fs[row] = s + b_a[0];
}

// h0 = tanh(fm @ w_h + b_h) -> xh0 h-slot ; c0 = tanh(fm @ w_c + b_c) -> c
__global__ void k_init(const float* __restrict__ fm,
                       const float* __restrict__ w_h, const float* __restrict__ b_h,
                       const float* __restrict__ w_c, const float* __restrict__ b_c,
                       float* __restrict__ xh0, float* __restrict__ c) {
    __shared__ float a[F2];
    int b = blockIdx.x;
    for (int k = threadIdx.x; k < F2; k += 256) a[k] = fm[b * F2 + k];
    __syncthreads();
    int n = blockIdx.y * 256 + threadIdx.x;   // 0..511
    float sh = 0.f, sc = 0.f;
    for (int k = 0; k < F2; ++k) {
        float av = a[k];
        sh += av * w_h[(size_t)k * H + n];
        sc += av * w_c[(size_t)k * H + n];
    }
    xh0[(size_t)b * 1024 + 512 + n] = tanhf(sh + b_h[n]);
    c[(size_t)b * H + n]            = tanhf(sc + b_c[n]);
}

// attention + softmax + context chunk. grid (B, 8), 256 threads.
// reads h from xh[b][512..1023], writes ctx to xh[b][fc*64 .. fc*64+63]
__global__ void k_attn(const float* __restrict__ X, const float* __restrict__ fscore,
                       const float* __restrict__ w_a_h, float* __restrict__ xh,
                       float* __restrict__ out_a, int t) {
    __shared__ float red[12];        // 0..3 hsum, 4..7 max, 8..11 expsum
    __shared__ float sal[224];
    __shared__ float spart[4][64];
    int b = blockIdx.x, fc = blockIdx.y, tid = threadIdx.x;
    int lane = tid & 63, wid = tid >> 6;

    // hscore = h[b] . w_a_h  (each thread 2 elems, wave shfl reduce)
    const float* hb = xh + (size_t)b * 1024 + 512;
    float p = hb[tid] * w_a_h[tid] + hb[tid + 256] * w_a_h[tid + 256];
    for (int off = 32; off > 0; off >>= 1) p += __shfl_down(p, off);
    if (lane == 0) red[wid] = p;
    __syncthreads();
    float hs = red[0] + red[1] + red[2] + red[3];

    // score + softmax over L
    float scv = (tid < L) ? tanhf(hs + fscore[b * L + tid]) : -3.0e38f;
    float m = scv;
    for (int off = 32; off > 0; off >>= 1) m = fmaxf(m, __shfl_down(m, off));
    if (lane == 0) red[4 + wid] = m;
    __syncthreads();
    float mx = fmaxf(fmaxf(red[4], red[5]), fmaxf(red[6], red[7]));
    float ex = (tid < L) ? expf(scv - mx) : 0.f;
    float sm = ex;
    for (int off = 32; off > 0; off >>= 1) sm += __shfl_down(sm, off);
    if (lane == 0) red[8 + wid] = sm;
    __syncthreads();
    float denom = red[8] + red[9] + red[10] + red[11];
    float al = ex / denom;
    if (tid < L) {
        sal[tid] = al;
        if (fc == 0) out_a[((size_t)b * T + t) * L + tid] = al;
    }
    __syncthreads();

    // context chunk: f = fc*64 + (tid&63), L split over 4 l-groups of 49
    int fi = tid & 63, lg = tid >> 6;
    int f = fc * 64 + fi;
    const float* xp = X + (size_t)b * L * F2 + f;
    float acc = 0.f;
    int l0 = lg * 49;
    for (int li = 0; li < 49; ++li) acc += xp[(size_t)(l0 + li) * F2] * sal[l0 + li];
    spart[lg][fi] = acc;
    __syncthreads();
    if (tid < 64)
        xh[(size_t)b * 1024 + fc * 64 + tid] =
            spart[0][tid] + spart[1][tid] + spart[2][tid] + spart[3][tid];
}

// split-K GEMM: zpart[ks] = A_chunk @ W_chunk.  M=128 (batch), N=2048, K=1280.
// grid (N/64=32, M/64=2, KS=8), 256 threads, 4x4 per-thread tile.
// A row b: [ctx(512)|h(512)] from xh, word(256) direct. W rows: [k_w 256..767; r_w; k_w 0..255]
__global__ void k_gemm(const float* __restrict__ xh, const float* __restrict__ word,
                       const float* __restrict__ k_w, const float* __restrict__ r_w,
                       float* __restrict__ zpart, int t) {
    __shared__ float As[BK][68];   // [kk][m]
    __shared__ float Bs[BK][68];   // [kk][n]
    int tid = threadIdx.x;
    int tr = tid >> 4, tc = tid & 15;
    int rowbase = blockIdx.y * 64;
    int nbase = blockIdx.x * 64;
    int ks = blockIdx.z;
    float acc[4][4] = {};

    // staging assignments
    int lr = tid >> 2, lk = (tid & 3) * 8;      // A: row lr (0..63), k off lk
    int bkr = tid >> 3, bc8 = (tid & 7) * 8;    // B: k row bkr (0..31), col off bc8

    for (int it = 0; it < KCHUNK / BK; ++it) {
        int kbase = ks * KCHUNK + it * BK;

        // global loads to regs first (latency overlap with previous compute)
        int gb = rowbase + lr;
        int gk = kbase + lk;
        float4 a0, a1;
        if (gk < 1024) {
            const float* p = xh + (size_t)gb * 1024 + gk;
            a0 = *(const float4*)p; a1 = *(const float4*)(p + 4);
        } else {
            const float* p = word + ((size_t)gb * T + t) * D + (gk - 1024);
            a0 = *(const float4*)p; a1 = *(const float4*)(p + 4);
        }
        int kr = kbase + bkr;
        const float* wrow;
        if (kr < 512)       wrow = k_w + (size_t)(256 + kr) * H4;
        else if (kr < 1024) wrow = r_w + (size_t)(kr - 512) * H4;
        else                wrow = k_w + (size_t)(kr - 1024) * H4;
        const float* bp = wrow + nbase + bc8;
        float4 b0 = *(const float4*)bp;
        float4 b1 = *(const float4*)(bp + 4);

        __syncthreads();
        As[lk + 0][lr] = a0.x; As[lk + 1][lr] = a0.y; As[lk + 2][lr] = a0.z; As[lk + 3][lr] = a0.w;
        As[lk + 4][lr] = a1.x; As[lk + 5][lr] = a1.y; As[lk + 6][lr] = a1.z; As[lk + 7][lr] = a1.w;
        *(float4*)&Bs[bkr][bc8] = b0;
        *(float4*)&Bs[bkr][bc8 + 4] = b1;
        __syncthreads();

        #pragma unroll
        for (int kk = 0; kk < BK; ++kk) {
            float4 av = *(const float4*)&As[kk][tr * 4];
            float4 bv = *(const float4*)&Bs[kk][tc * 4];
            acc[0][0] += av.x * bv.x; acc[0][1] += av.x * bv.y; acc[0][2] += av.x * bv.z; acc[0][3] += av.x * bv.w;
            acc[1][0] += av.y * bv.x; acc[1][1] += av.y * bv.y; acc[1][2] += av.y * bv.z; acc[1][3] += av.y * bv.w;
            acc[2][0] += av.z * bv.x; acc[2][1] += av.z * bv.y; acc[2][2] += av.z * bv.z; acc[2][3] += av.z * bv.w;
            acc[3][0] += av.w * bv.x; acc[3][1] += av.w * bv.y; acc[3][2] += av.w * bv.z; acc[3][3] += av.w * bv.w;
        }
    }

    float* zp = zpart + (size_t)ks * B * H4;
    #pragma unroll
    for (int i = 0; i < 4; ++i) {
        float4 v0 = make_float4(acc[i][0], acc[i][1], acc[i][2], acc[i][3]);
        *(float4*)&zp[(size_t)(rowbase + tr * 4 + i) * H4 + nbase + tc * 4] = v0;
    }
}

// reduce split-K partials + bias, LSTM cell, write h/c/outputs.
// grid (H/256=2, B), 256 threads.
__global__ void k_cell(const float* __restrict__ zpart, const float* __restrict__ bias,
                       float* __restrict__ xh_next, float* __restrict__ c,
                       float* __restrict__ hiddens, float* __restrict__ memory, int t) {
    int n = blockIdx.x * 256 + threadIdx.x;
    int b = blockIdx.y;
    float z[4];
    #pragma unroll
    for (int g = 0; g < 4; ++g) z[g] = bias[g * H + n];
    #pragma unroll
    for (int ksi = 0; ksi < KS; ++ksi) {
        const float* zp = zpart + ((size_t)ksi * B + b) * H4;
        #pragma unroll
        for (int g = 0; g < 4; ++g) z[g] += zp[g * H + n];
    }
    float cv = c[(size_t)b * H + n];
    float cn = sigf(z[1]) * cv + sigf(z[0]) * tanhf(z[2]);
    float hn = sigf(z[3]) * tanhf(cn);
    c[(size_t)b * H + n] = cn;
    xh_next[(size_t)b * 1024 + 512 + n] = hn;
    hiddens[((size_t)b * T + t) * H + n] = hn;
    memory[((size_t)t * B + b) * H + n] = cn;
}

extern "C" void kernel_launch(void* const* d_in, const int* in_sizes, int n_in,
                              void* d_out, int out_size, void* d_ws, size_t ws_size,
                              hipStream_t stream) {
    (void)in_sizes; (void)n_in; (void)out_size; (void)ws_size;
    const float* X      = (const float*)d_in[0];
    const float* word   = (const float*)d_in[1];
    const float* w_h    = (const float*)d_in[2];
    const float* b_h    = (const float*)d_in[3];
    const float* w_c    = (const float*)d_in[4];
    const float* b_c    = (const float*)d_in[5];
    const float* w_a_h  = (const float*)d_in[6];
    const float* w_a    = (const float*)d_in[7];
    const float* b_a    = (const float*)d_in[8];
    const float* k_w    = (const float*)d_in[9];   // [768, 2048]
    const float* r_w    = (const float*)d_in[10];  // [512, 2048]
    const float* bias   = (const float*)d_in[11];  // [2048]

    float* out_h = (float*)d_out;                        // [B,T,H]
    float* out_m = out_h + (size_t)B * T * H;            // [T,B,H]
    float* out_a = out_m + (size_t)T * B * H;            // [B,T,L]

    // ws layout (floats): zpart[KS*B*H4] fm[B*F2] fscore[B*L] c[B*H] xh0[B*1024] xh1[B*1024]
    float* ws     = (float*)d_ws;
    float* zpart  = ws;
    float* fm     = zpart + (size_t)KS * B * H4;
    float* fscore = fm + (size_t)B * F2;
    float* cbuf   = fscore + (size_t)B * L;
    float* xh0    = cbuf + (size_t)B * H;
    float* xh1    = xh0 + (size_t)B * 1024;

    k_mean<<<B, 256, 0, stream>>>(X, fm);
    k_fscore<<<(B * L) / 4, 256, 0, stream>>>(X, w_a, b_a, fscore);
    k_init<<<dim3(B, 2), 256, 0, stream>>>(fm, w_h, b_h, w_c, b_c, xh0, cbuf);

    for (int t = 0; t < T; ++t) {
        float* cur = (t & 1) ? xh1 : xh0;
        float* nxt = (t & 1) ? xh0 : xh1;
        k_attn<<<dim3(B, 8), 256, 0, stream>>>(X, fscore, w_a_h, cur, out_a, t);
        k_gemm<<<dim3(32, 2, KS), 256, 0, stream>>>(cur, word, k_w, r_w, zpart, t);
        k_cell<<<dim3(2, B), 256, 0, stream>>>(zpart, bias, nxt, cbuf, out_h, out_m, t);
    }
}

// Round 3
// 917.365 us; speedup vs baseline: 7.3905x; 1.0619x over previous
//
#include <hip/hip_runtime.h>
#include <math.h>

#define B  128
#define L  196
#define F2 512
#define T  32
#define D  256
#define H  512
#define H4 2048
#define KCAT 1280
#define KS 4
#define KCHUNK 320   // KCAT/KS

typedef __attribute__((ext_vector_type(8))) short bf16x8;
typedef __attribute__((ext_vector_type(4))) float f32x4;

__device__ __forceinline__ float sigf(float x) { return 1.0f / (1.0f + expf(-x)); }
__device__ __forceinline__ unsigned short f2bf(float x) {
    unsigned u = __float_as_uint(x);
    u += 0x7FFF + ((u >> 16) & 1);
    return (unsigned short)(u >> 16);
}
__device__ __forceinline__ float bf2f(unsigned short s) {
    return __uint_as_float(((unsigned)s) << 16);
}
__device__ __forceinline__ float wred_sum(float v) {
    for (int o = 32; o > 0; o >>= 1) v += __shfl_down(v, o);
    return v;
}
__device__ __forceinline__ float wred_max(float v) {
    for (int o = 32; o > 0; o >>= 1) v = fmaxf(v, __shfl_down(v, o));
    return v;
}

// ---------- setup kernels ----------

// features mean over l -> bf16. grid (B, 4), 256 thr
__global__ void k_mean(const float* __restrict__ X, unsigned short* __restrict__ fmb) {
    __shared__ float sp[2][128];
    int b = blockIdx.x, fc = blockIdx.y, tid = threadIdx.x;
    int fi = tid & 127, lg = tid >> 7;
    int f = fc * 128 + fi;
    const float* xp = X + (size_t)b * L * F2 + f;
    float s = 0.f;
    for (int l = lg; l < L; l += 2) s += xp[(size_t)l * F2];
    sp[lg][fi] = s;
    __syncthreads();
    if (tid < 128)
        fmb[b * F2 + fc * 128 + tid] = f2bf((sp[0][tid] + sp[1][tid]) * (1.0f / L));
}

// cast X->bf16 + feat_score. grid (B*L/8), 256 thr (8 rows/block, 32 lanes/row)
__global__ void k_prep(const float* __restrict__ X, const float* __restrict__ w_a,
                       const float* __restrict__ b_a,
                       unsigned short* __restrict__ Xb, float* __restrict__ fscore) {
    int tid = threadIdx.x;
    int rowi = tid >> 5, lane32 = tid & 31;
    size_t row = (size_t)blockIdx.x * 8 + rowi;
    const float* src = X + row * F2;
    unsigned short* dst = Xb + row * F2;
    float s = 0.f;
    #pragma unroll
    for (int j = 0; j < 4; ++j) {
        int f = j * 128 + lane32 * 4;
        float4 v = *(const float4*)(src + f);
        float4 w = *(const float4*)(w_a + f);
        s += v.x * w.x + v.y * w.y + v.z * w.z + v.w * w.w;
        ushort4 u;
        u.x = f2bf(v.x); u.y = f2bf(v.y); u.z = f2bf(v.z); u.w = f2bf(v.w);
        *(ushort4*)(dst + f) = u;
    }
    for (int o = 16; o > 0; o >>= 1) s += __shfl_down(s, o, 32);
    if (lane32 == 0) fscore[row] = s + b_a[0];
}

// word fp32 -> bf16. grid 512, 256 thr, 8/thread
__global__ void k_castw(const float* __restrict__ src, unsigned short* __restrict__ dst) {
    size_t i = ((size_t)blockIdx.x * 256 + threadIdx.x) * 8;
    float4 v0 = *(const float4*)(src + i);
    float4 v1 = *(const float4*)(src + i + 4);
    ushort4 u0, u1;
    u0.x = f2bf(v0.x); u0.y = f2bf(v0.y); u0.z = f2bf(v0.z); u0.w = f2bf(v0.w);
    u1.x = f2bf(v1.x); u1.y = f2bf(v1.y); u1.z = f2bf(v1.z); u1.w = f2bf(v1.w);
    *(ushort4*)(dst + i) = u0;
    *(ushort4*)(dst + i + 4) = u1;
}

// transpose-cast: dst[c][colOff + r] = bf16(src[r][c]).  grid (nRows/32, srcLD/64)
__global__ void k_tr(const float* __restrict__ src, int srcLD,
                     unsigned short* __restrict__ dst, int dstLD, int colOff) {
    __shared__ float Ls[32][65];
    int r0 = blockIdx.x * 32, c0 = blockIdx.y * 64;
    int tid = threadIdx.x;
    int r = tid >> 3, c8 = (tid & 7) * 8;
    const float* s = src + (size_t)(r0 + r) * srcLD + c0 + c8;
    #pragma unroll
    for (int j = 0; j < 8; ++j) Ls[r][c8 + j] = s[j];
    __syncthreads();
    int cc = tid >> 2, q = tid & 3;
    unsigned short tmp[8];
    #pragma unroll
    for (int j = 0; j < 8; ++j) tmp[j] = f2bf(Ls[q * 8 + j][cc]);
    *(float4*)(dst + (size_t)(c0 + cc) * dstLD + colOff + r0 + q * 8) = *(float4*)tmp;
}

// ---------- init-state GEMM (MFMA): [fm @ wi] -> tanh -> h0 (bf16->Abuf0) / c0 (fp32) ----------
// M=128, K=512, N=1024 ([w_h | w_c] cols). grid (8), 256 thr, tile 128x128.
__global__ __launch_bounds__(256) void k_init_gemm(
    const unsigned short* __restrict__ A,    // fm_bf16 [128][512]
    const unsigned short* __restrict__ Bt,   // wiT [1024][512]
    const float* __restrict__ b_h, const float* __restrict__ b_c,
    unsigned short* __restrict__ Abuf0, float* __restrict__ cbuf) {
    __shared__ short As[128 * 64];
    __shared__ short Bs[128 * 64];
    int tid = threadIdx.x;
    int nbase = blockIdx.x * 128;
    int wave = tid >> 6, lane = tid & 63;
    int wm = (wave >> 1) * 64, wn = (wave & 1) * 64;
    int l15 = lane & 15, l4 = lane >> 4;

    f32x4 acc[4][4];
    #pragma unroll
    for (int i = 0; i < 4; ++i)
        #pragma unroll
        for (int j = 0; j < 4; ++j) acc[i][j] = (f32x4){0.f, 0.f, 0.f, 0.f};

    for (int it = 0; it < 8; ++it) {
        int kbase = it * 64;
        #pragma unroll
        for (int ch = 0; ch < 4; ++ch) {
            int idx = ch * 256 + tid;
            int row = idx >> 3, q = idx & 7;
            int k = kbase + q * 8;
            float4 v = *(const float4*)(A + (size_t)row * 512 + k);
            *(float4*)&As[row * 64 + ((q ^ (row & 7)) << 3)] = v;
            float4 w = *(const float4*)(Bt + (size_t)(nbase + row) * 512 + k);
            *(float4*)&Bs[row * 64 + ((q ^ (row & 7)) << 3)] = w;
        }
        __syncthreads();
        #pragma unroll
        for (int ks = 0; ks < 2; ++ks) {
            bf16x8 a[4], b[4];
            #pragma unroll
            for (int f = 0; f < 4; ++f) {
                int ar = wm + f * 16 + l15;
                int q = ks * 4 + l4;
                a[f] = *(const bf16x8*)&As[ar * 64 + ((q ^ (ar & 7)) << 3)];
                int br = wn + f * 16 + l15;
                b[f] = *(const bf16x8*)&Bs[br * 64 + ((q ^ (br & 7)) << 3)];
            }
            #pragma unroll
            for (int fm = 0; fm < 4; ++fm)
                #pragma unroll
                for (int fn = 0; fn < 4; ++fn)
                    acc[fm][fn] = __builtin_amdgcn_mfma_f32_16x16x32_bf16(a[fm], b[fn], acc[fm][fn], 0, 0, 0);
        }
        __syncthreads();
    }
    #pragma unroll
    for (int fm = 0; fm < 4; ++fm)
        #pragma unroll
        for (int j = 0; j < 4; ++j) {
            int m = wm + fm * 16 + l4 * 4 + j;
            #pragma unroll
            for (int fn = 0; fn < 4; ++fn) {
                int gn = nbase + wn + fn * 16 + l15;
                float v = acc[fm][fn][j];
                if (gn < 512) Abuf0[(size_t)m * 1024 + 512 + gn] = f2bf(tanhf(v + b_h[gn]));
                else          cbuf[(size_t)m * 512 + gn - 512] = tanhf(v + b_c[gn - 512]);
            }
        }
}

// ---------- per-step gates GEMM (MFMA, split-K) ----------
// zpart[ks][m][n] = A[m][ks-chunk] @ W[ks-chunk][n].  grid (16, KS), 256 thr.
__global__ __launch_bounds__(256) void k_gemm(
    const unsigned short* __restrict__ Abuf,   // [128][1024] ctx|h
    const unsigned short* __restrict__ wordb,  // [128][32][256]
    const unsigned short* __restrict__ WcatT,  // [2048][1280]
    float* __restrict__ zpart, int t) {
    __shared__ short As[128 * 64];
    __shared__ short Bs[128 * 64];
    int tid = threadIdx.x;
    int nbase = blockIdx.x * 128;
    int ksb = blockIdx.y;
    int wave = tid >> 6, lane = tid & 63;
    int wm = (wave >> 1) * 64, wn = (wave & 1) * 64;
    int l15 = lane & 15, l4 = lane >> 4;

    f32x4 acc[4][4];
    #pragma unroll
    for (int i = 0; i < 4; ++i)
        #pragma unroll
        for (int j = 0; j < 4; ++j) acc[i][j] = (f32x4){0.f, 0.f, 0.f, 0.f};

    for (int it = 0; it < KCHUNK / 64; ++it) {
        int kbase = ksb * KCHUNK + it * 64;
        #pragma unroll
        for (int ch = 0; ch < 4; ++ch) {
            int idx = ch * 256 + tid;
            int row = idx >> 3, q = idx & 7;
            int k = kbase + q * 8;
            float4 v;
            if (k < 1024) v = *(const float4*)(Abuf + (size_t)row * 1024 + k);
            else          v = *(const float4*)(wordb + ((size_t)row * T + t) * D + (k - 1024));
            *(float4*)&As[row * 64 + ((q ^ (row & 7)) << 3)] = v;
            float4 w = *(const float4*)(WcatT + (size_t)(nbase + row) * KCAT + k);
            *(float4*)&Bs[row * 64 + ((q ^ (row & 7)) << 3)] = w;
        }
        __syncthreads();
        #pragma unroll
        for (int ks = 0; ks < 2; ++ks) {
            bf16x8 a[4], b[4];
            #pragma unroll
            for (int f = 0; f < 4; ++f) {
                int ar = wm + f * 16 + l15;
                int q = ks * 4 + l4;
                a[f] = *(const bf16x8*)&As[ar * 64 + ((q ^ (ar & 7)) << 3)];
                int br = wn + f * 16 + l15;
                b[f] = *(const bf16x8*)&Bs[br * 64 + ((q ^ (br & 7)) << 3)];
            }
            #pragma unroll
            for (int fm = 0; fm < 4; ++fm)
                #pragma unroll
                for (int fn = 0; fn < 4; ++fn)
                    acc[fm][fn] = __builtin_amdgcn_mfma_f32_16x16x32_bf16(a[fm], b[fn], acc[fm][fn], 0, 0, 0);
        }
        __syncthreads();
    }
    float* zp = zpart + (size_t)ksb * B * H4;
    #pragma unroll
    for (int fm = 0; fm < 4; ++fm)
        #pragma unroll
        for (int j = 0; j < 4; ++j) {
            int m = wm + fm * 16 + l4 * 4 + j;
            #pragma unroll
            for (int fn = 0; fn < 4; ++fn) {
                int n = nbase + wn + fn * 16 + l15;
                zp[(size_t)m * H4 + n] = acc[fm][fn][j];
            }
        }
}

// ---------- fused cell + attention, one block per batch row ----------
__global__ __launch_bounds__(256) void k_step(
    const float* __restrict__ zpart, const float* __restrict__ bias,
    float* __restrict__ cbuf, unsigned short* __restrict__ Abuf_dst,
    const unsigned short* __restrict__ Xb, const float* __restrict__ fscore,
    const float* __restrict__ w_a_h,
    float* __restrict__ out_h, float* __restrict__ out_m, float* __restrict__ out_a,
    int t_next) {
    __shared__ float red[12];
    __shared__ float sal[196];
    int b = blockIdx.x, tid = threadIdx.x;
    int lane = tid & 63, wid = tid >> 6;
    int n0 = tid * 2;
    float hp;
    if (t_next > 0) {
        float2 z[4];
        #pragma unroll
        for (int g = 0; g < 4; ++g) z[g] = *(const float2*)(bias + g * H + n0);
        #pragma unroll
        for (int ks = 0; ks < KS; ++ks) {
            const float* zp = zpart + ((size_t)ks * B + b) * H4;
            #pragma unroll
            for (int g = 0; g < 4; ++g) {
                float2 v = *(const float2*)(zp + g * H + n0);
                z[g].x += v.x; z[g].y += v.y;
            }
        }
        float2 cv = *(const float2*)(cbuf + (size_t)b * H + n0);
        float cnx = sigf(z[1].x) * cv.x + sigf(z[0].x) * tanhf(z[2].x);
        float cny = sigf(z[1].y) * cv.y + sigf(z[0].y) * tanhf(z[2].y);
        float hnx = sigf(z[3].x) * tanhf(cnx);
        float hny = sigf(z[3].y) * tanhf(cny);
        *(float2*)(cbuf + (size_t)b * H + n0) = make_float2(cnx, cny);
        int tp = t_next - 1;
        *(float2*)(out_m + ((size_t)tp * B + b) * H + n0) = make_float2(cnx, cny);
        *(float2*)(out_h + ((size_t)b * T + tp) * H + n0) = make_float2(hnx, hny);
        ushort2 hu; hu.x = f2bf(hnx); hu.y = f2bf(hny);
        *(ushort2*)(Abuf_dst + (size_t)b * 1024 + 512 + n0) = hu;
        hp = hnx * w_a_h[n0] + hny * w_a_h[n0 + 1];
    } else {
        ushort2 hu = *(const ushort2*)(Abuf_dst + (size_t)b * 1024 + 512 + n0);
        hp = bf2f(hu.x) * w_a_h[n0] + bf2f(hu.y) * w_a_h[n0 + 1];
    }
    float s = wred_sum(hp);
    if (lane == 0) red[wid] = s;
    __syncthreads();
    float hs = red[0] + red[1] + red[2] + red[3];
    if (t_next >= T) return;

    float scv = (tid < L) ? tanhf(hs + fscore[b * L + tid]) : -3.0e38f;
    float m = wred_max(scv);
    if (lane == 0) red[4 + wid] = m;
    __syncthreads();
    float mx = fmaxf(fmaxf(red[4], red[5]), fmaxf(red[6], red[7]));
    float ex = (tid < L) ? expf(scv - mx) : 0.f;
    float es = wred_sum(ex);
    if (lane == 0) red[8 + wid] = es;
    __syncthreads();
    float denom = red[8] + red[9] + red[10] + red[11];
    float al = ex / denom;
    if (tid < L) {
        sal[tid] = al;
        out_a[((size_t)b * T + t_next) * L + tid] = al;
    }
    __syncthreads();

    int f0 = tid * 2;
    const unsigned short* xb = Xb + (size_t)b * L * F2 + f0;
    float a0 = 0.f, a1 = 0.f;
    #pragma unroll 4
    for (int l = 0; l < L; ++l) {
        unsigned u = *(const unsigned*)(xb + (size_t)l * F2);
        float w = sal[l];
        a0 += bf2f((unsigned short)(u & 0xFFFF)) * w;
        a1 += bf2f((unsigned short)(u >> 16)) * w;
    }
    ushort2 cv2; cv2.x = f2bf(a0); cv2.y = f2bf(a1);
    *(ushort2*)(Abuf_dst + (size_t)b * 1024 + f0) = cv2;
}

extern "C" void kernel_launch(void* const* d_in, const int* in_sizes, int n_in,
                              void* d_out, int out_size, void* d_ws, size_t ws_size,
                              hipStream_t stream) {
    (void)in_sizes; (void)n_in; (void)out_size; (void)ws_size;
    const float* X     = (const float*)d_in[0];
    const float* word  = (const float*)d_in[1];
    const float* w_h   = (const float*)d_in[2];
    const float* w_c   = (const float*)d_in[4];
    const float* b_h   = (const float*)d_in[3];
    const float* b_c   = (const float*)d_in[5];
    const float* w_a_h = (const float*)d_in[6];
    const float* w_a   = (const float*)d_in[7];
    const float* b_a   = (const float*)d_in[8];
    const float* k_w   = (const float*)d_in[9];
    const float* r_w   = (const float*)d_in[10];
    const float* bias  = (const float*)d_in[11];

    float* out_h = (float*)d_out;
    float* out_m = out_h + (size_t)B * T * H;
    float* out_a = out_m + (size_t)T * B * H;

    char* p = (char*)d_ws;
    unsigned short* Xb    = (unsigned short*)p; p += (size_t)B * L * F2 * 2;
    unsigned short* WcatT = (unsigned short*)p; p += (size_t)H4 * KCAT * 2;
    unsigned short* wiT   = (unsigned short*)p; p += (size_t)1024 * 512 * 2;
    unsigned short* wordb = (unsigned short*)p; p += (size_t)B * T * D * 2;
    unsigned short* fmb   = (unsigned short*)p; p += (size_t)B * F2 * 2;
    unsigned short* Abuf0 = (unsigned short*)p; p += (size_t)B * 1024 * 2;
    unsigned short* Abuf1 = (unsigned short*)p; p += (size_t)B * 1024 * 2;
    float* fscore = (float*)p; p += (size_t)B * L * 4;
    float* cbuf   = (float*)p; p += (size_t)B * H * 4;
    float* zpart  = (float*)p; p += (size_t)KS * B * H4 * 4;

    k_mean<<<dim3(B, 4), 256, 0, stream>>>(X, fmb);
    k_prep<<<(B * L) / 8, 256, 0, stream>>>(X, w_a, b_a, Xb, fscore);
    k_castw<<<512, 256, 0, stream>>>(word, wordb);
    // WcatT rows n, cols k: [k_w 256..767 ; r_w ; k_w 0..255]
    k_tr<<<dim3(16, 32), 256, 0, stream>>>(k_w + (size_t)256 * H4, H4, WcatT, KCAT, 0);
    k_tr<<<dim3(16, 32), 256, 0, stream>>>(r_w, H4, WcatT, KCAT, 512);
    k_tr<<<dim3(8, 32), 256, 0, stream>>>(k_w, H4, WcatT, KCAT, 1024);
    // wiT rows: 0..511 = w_h cols, 512..1023 = w_c cols
    k_tr<<<dim3(16, 8), 256, 0, stream>>>(w_h, 512, wiT, 512, 0);
    k_tr<<<dim3(16, 8), 256, 0, stream>>>(w_c, 512, wiT + (size_t)512 * 512, 512, 0);

    k_init_gemm<<<8, 256, 0, stream>>>(fmb, wiT, b_h, b_c, Abuf0, cbuf);
    k_step<<<B, 256, 0, stream>>>(zpart, bias, cbuf, Abuf0, Xb, fscore, w_a_h,
                                  out_h, out_m, out_a, 0);
    for (int t = 0; t < T; ++t) {
        unsigned short* cur = (t & 1) ? Abuf1 : Abuf0;
        unsigned short* nxt = (t & 1) ? Abuf0 : Abuf1;
        k_gemm<<<dim3(16, KS), 256, 0, stream>>>(cur, wordb, WcatT, zpart, t);
        k_step<<<B, 256, 0, stream>>>(zpart, bias, cbuf, nxt, Xb, fscore, w_a_h,
                                      out_h, out_m, out_a, t + 1);
    }
}

// Round 5
// 555.001 us; speedup vs baseline: 12.2158x; 1.6529x over previous
//
#include <hip/hip_runtime.h>
#include <math.h>

#define B  128
#define L  196
#define F2 512
#define T  32
#define D  256
#define H  512
#define H4 2048
#define KCAT 1280
#define KS 4
#define KCHUNK 320   // KCAT/KS

typedef __attribute__((ext_vector_type(8))) short bf16x8;
typedef __attribute__((ext_vector_type(4))) float f32x4;

__device__ __forceinline__ float sigf(float x) { return 1.0f / (1.0f + expf(-x)); }
__device__ __forceinline__ unsigned short f2bf(float x) {
    unsigned u = __float_as_uint(x);
    u += 0x7FFF + ((u >> 16) & 1);
    return (unsigned short)(u >> 16);
}
__device__ __forceinline__ float bf2f(unsigned short s) {
    return __uint_as_float(((unsigned)s) << 16);
}
__device__ __forceinline__ float wred_sum(float v) {
    for (int o = 32; o > 0; o >>= 1) v += __shfl_down(v, o);
    return v;
}
__device__ __forceinline__ float wred_max(float v) {
    for (int o = 32; o > 0; o >>= 1) v = fmaxf(v, __shfl_down(v, o));
    return v;
}

// ---------- setup ----------

// fused: X->bf16 cast, feat_score, 7-way mean partials. grid (B, 7), 256 thr.
// Each block: 28 consecutive l rows, processed in 4 strips of 8 (last strip 4).
__global__ void k_prep2(const float* __restrict__ X, const float* __restrict__ w_a,
                        const float* __restrict__ b_a, unsigned short* __restrict__ Xb,
                        float* __restrict__ fscore, float* __restrict__ fmpart) {
    __shared__ float sp[8][512];
    int b = blockIdx.x, g = blockIdx.y, tid = threadIdx.x;
    int rowi = tid >> 5, lane32 = tid & 31;
    int f0 = tid * 2;
    float2 acc = make_float2(0.f, 0.f);
    for (int s = 0; s < 4; ++s) {
        int li = s * 8 + rowi;
        float4 part[4];
        if (li < 28) {
            size_t row = (size_t)b * L + g * 28 + li;
            const float* src = X + row * F2;
            unsigned short* dst = Xb + row * F2;
            float sc = 0.f;
            #pragma unroll
            for (int j = 0; j < 4; ++j) {
                int f = j * 128 + lane32 * 4;
                float4 v = *(const float4*)(src + f);
                float4 w = *(const float4*)(w_a + f);
                sc += v.x * w.x + v.y * w.y + v.z * w.z + v.w * w.w;
                part[j] = v;
                ushort4 u;
                u.x = f2bf(v.x); u.y = f2bf(v.y); u.z = f2bf(v.z); u.w = f2bf(v.w);
                *(ushort4*)(dst + f) = u;
            }
            for (int o = 16; o > 0; o >>= 1) sc += __shfl_down(sc, o, 32);
            if (lane32 == 0) fscore[row] = sc + b_a[0];
        } else {
            #pragma unroll
            for (int j = 0; j < 4; ++j) part[j] = make_float4(0.f, 0.f, 0.f, 0.f);
        }
        __syncthreads();
        #pragma unroll
        for (int j = 0; j < 4; ++j)
            *(float4*)&sp[rowi][j * 128 + lane32 * 4] = part[j];
        __syncthreads();
        #pragma unroll
        for (int r = 0; r < 8; ++r) { acc.x += sp[r][f0]; acc.y += sp[r][f0 + 1]; }
    }
    *(float2*)&fmpart[((size_t)b * 7 + g) * 512 + f0] = acc;
}

// reduce 7 mean-partials -> bf16 fm. grid (B), 256 thr.
__global__ void k_mred(const float* __restrict__ fmpart, unsigned short* __restrict__ fmb) {
    int b = blockIdx.x, tid = threadIdx.x;
    int f0 = tid * 2;
    float2 acc = make_float2(0.f, 0.f);
    #pragma unroll
    for (int g = 0; g < 7; ++g) {
        float2 v = *(const float2*)&fmpart[((size_t)b * 7 + g) * 512 + f0];
        acc.x += v.x; acc.y += v.y;
    }
    ushort2 u; u.x = f2bf(acc.x * (1.0f / L)); u.y = f2bf(acc.y * (1.0f / L));
    *(ushort2*)(fmb + (size_t)b * F2 + f0) = u;
}

// word fp32 -> bf16. grid 512, 256 thr, 8/thread
__global__ void k_castw(const float* __restrict__ src, unsigned short* __restrict__ dst) {
    size_t i = ((size_t)blockIdx.x * 256 + threadIdx.x) * 8;
    float4 v0 = *(const float4*)(src + i);
    float4 v1 = *(const float4*)(src + i + 4);
    ushort4 u0, u1;
    u0.x = f2bf(v0.x); u0.y = f2bf(v0.y); u0.z = f2bf(v0.z); u0.w = f2bf(v0.w);
    u1.x = f2bf(v1.x); u1.y = f2bf(v1.y); u1.z = f2bf(v1.z); u1.w = f2bf(v1.w);
    *(ushort4*)(dst + i) = u0;
    *(ushort4*)(dst + i + 4) = u1;
}

// transpose-cast all 3 W chunks into WcatT. grid (16, 32, 3).
__global__ void k_trW(const float* __restrict__ k_w, const float* __restrict__ r_w,
                      unsigned short* __restrict__ WcatT) {
    int job = blockIdx.z;
    if (job == 2 && blockIdx.x >= 8) return;
    const float* src; int colOff;
    if (job == 0)      { src = k_w + (size_t)256 * H4; colOff = 0; }
    else if (job == 1) { src = r_w;                    colOff = 512; }
    else               { src = k_w;                    colOff = 1024; }
    __shared__ float Ls[32][65];
    int r0 = blockIdx.x * 32, c0 = blockIdx.y * 64;
    int tid = threadIdx.x;
    int r = tid >> 3, c8 = (tid & 7) * 8;
    const float* s = src + (size_t)(r0 + r) * H4 + c0 + c8;
    #pragma unroll
    for (int j = 0; j < 8; ++j) Ls[r][c8 + j] = s[j];
    __syncthreads();
    int cc = tid >> 2, q = tid & 3;
    unsigned short tmp[8];
    #pragma unroll
    for (int j = 0; j < 8; ++j) tmp[j] = f2bf(Ls[q * 8 + j][cc]);
    *(float4*)(WcatT + (size_t)(c0 + cc) * KCAT + colOff + r0 + q * 8) = *(float4*)tmp;
}

// transpose-cast w_h / w_c into wiT. grid (16, 8, 2).
__global__ void k_trI(const float* __restrict__ w_h, const float* __restrict__ w_c,
                      unsigned short* __restrict__ wiT) {
    int job = blockIdx.z;
    const float* src = job ? w_c : w_h;
    unsigned short* dst = wiT + (size_t)job * 512 * 512;
    __shared__ float Ls[32][65];
    int r0 = blockIdx.x * 32, c0 = blockIdx.y * 64;
    int tid = threadIdx.x;
    int r = tid >> 3, c8 = (tid & 7) * 8;
    const float* s = src + (size_t)(r0 + r) * 512 + c0 + c8;
    #pragma unroll
    for (int j = 0; j < 8; ++j) Ls[r][c8 + j] = s[j];
    __syncthreads();
    int cc = tid >> 2, q = tid & 3;
    unsigned short tmp[8];
    #pragma unroll
    for (int j = 0; j < 8; ++j) tmp[j] = f2bf(Ls[q * 8 + j][cc]);
    *(float4*)(dst + (size_t)(c0 + cc) * 512 + r0 + q * 8) = *(float4*)tmp;
}

// ---------- init-state GEMM (MFMA, verified round 3) ----------
__global__ __launch_bounds__(256) void k_init_gemm(
    const unsigned short* __restrict__ A,    // fm_bf16 [128][512]
    const unsigned short* __restrict__ Bt,   // wiT [1024][512]
    const float* __restrict__ b_h, const float* __restrict__ b_c,
    unsigned short* __restrict__ Abuf0, float* __restrict__ cbuf) {
    __shared__ short As[128 * 64];
    __shared__ short Bs[128 * 64];
    int tid = threadIdx.x;
    int nbase = blockIdx.x * 128;
    int wave = tid >> 6, lane = tid & 63;
    int wm = (wave >> 1) * 64, wn = (wave & 1) * 64;
    int l15 = lane & 15, l4 = lane >> 4;

    f32x4 acc[4][4];
    #pragma unroll
    for (int i = 0; i < 4; ++i)
        #pragma unroll
        for (int j = 0; j < 4; ++j) acc[i][j] = (f32x4){0.f, 0.f, 0.f, 0.f};

    for (int it = 0; it < 8; ++it) {
        int kbase = it * 64;
        #pragma unroll
        for (int ch = 0; ch < 4; ++ch) {
            int idx = ch * 256 + tid;
            int row = idx >> 3, q = idx & 7;
            int k = kbase + q * 8;
            float4 v = *(const float4*)(A + (size_t)row * 512 + k);
            *(float4*)&As[row * 64 + ((q ^ (row & 7)) << 3)] = v;
            float4 w = *(const float4*)(Bt + (size_t)(nbase + row) * 512 + k);
            *(float4*)&Bs[row * 64 + ((q ^ (row & 7)) << 3)] = w;
        }
        __syncthreads();
        #pragma unroll
        for (int ks = 0; ks < 2; ++ks) {
            bf16x8 a[4], b[4];
            #pragma unroll
            for (int f = 0; f < 4; ++f) {
                int ar = wm + f * 16 + l15;
                int q = ks * 4 + l4;
                a[f] = *(const bf16x8*)&As[ar * 64 + ((q ^ (ar & 7)) << 3)];
                int br = wn + f * 16 + l15;
                b[f] = *(const bf16x8*)&Bs[br * 64 + ((q ^ (br & 7)) << 3)];
            }
            #pragma unroll
            for (int fm = 0; fm < 4; ++fm)
                #pragma unroll
                for (int fn = 0; fn < 4; ++fn)
                    acc[fm][fn] = __builtin_amdgcn_mfma_f32_16x16x32_bf16(a[fm], b[fn], acc[fm][fn], 0, 0, 0);
        }
        __syncthreads();
    }
    #pragma unroll
    for (int fm = 0; fm < 4; ++fm)
        #pragma unroll
        for (int j = 0; j < 4; ++j) {
            int m = wm + fm * 16 + l4 * 4 + j;
            #pragma unroll
            for (int fn = 0; fn < 4; ++fn) {
                int gn = nbase + wn + fn * 16 + l15;
                float v = acc[fm][fn][j];
                if (gn < 512) Abuf0[(size_t)m * 1024 + 512 + gn] = f2bf(tanhf(v + b_h[gn]));
                else          cbuf[(size_t)m * 512 + gn - 512] = tanhf(v + b_c[gn - 512]);
            }
        }
}

// ---------- per-step gates GEMM (MFMA, split-K). grid (128), 256 thr ----------
// bid -> (ksb = bid>>5, ntile = bid&15, rowtile = (bid>>4)&1). Tile 64x128.
__global__ __launch_bounds__(256) void k_gemm_sep(
    const unsigned short* __restrict__ Abuf,   // [128][1024] ctx|h
    const unsigned short* __restrict__ wordb,  // [128][32][256]
    const unsigned short* __restrict__ WcatT,  // [2048][1280]
    float* __restrict__ zpart, int t) {
    __shared__ short As[64 * 64];
    __shared__ short Bs[128 * 64];
    int tid = threadIdx.x;
    int bid = blockIdx.x;
    int ksb = bid >> 5, rem = bid & 31;
    int nbase = (rem & 15) * 128, rowbase = (rem >> 4) * 64;
    int wave = tid >> 6, lane = tid & 63;
    int wm = (wave & 1) * 32, wn = (wave >> 1) * 64;
    int l15 = lane & 15, l4 = lane >> 4;

    f32x4 acc[2][4];
    #pragma unroll
    for (int i = 0; i < 2; ++i)
        #pragma unroll
        for (int j = 0; j < 4; ++j) acc[i][j] = (f32x4){0.f, 0.f, 0.f, 0.f};

    for (int it = 0; it < KCHUNK / 64; ++it) {
        int kbase = ksb * KCHUNK + it * 64;
        #pragma unroll
        for (int p = 0; p < 2; ++p) {   // A: 64 rows x 64 k
            int idx = p * 256 + tid;
            int row = idx >> 3, q = idx & 7;
            int k = kbase + q * 8;
            int gr = rowbase + row;
            float4 v;
            if (k < 1024) v = *(const float4*)(Abuf + (size_t)gr * 1024 + k);
            else          v = *(const float4*)(wordb + ((size_t)gr * T + t) * D + (k - 1024));
            *(float4*)&As[row * 64 + ((q ^ (row & 7)) << 3)] = v;
        }
        #pragma unroll
        for (int p = 0; p < 4; ++p) {   // B: 128 rows x 64 k
            int idx = p * 256 + tid;
            int row = idx >> 3, q = idx & 7;
            float4 w = *(const float4*)(WcatT + (size_t)(nbase + row) * KCAT + kbase + q * 8);
            *(float4*)&Bs[row * 64 + ((q ^ (row & 7)) << 3)] = w;
        }
        __syncthreads();
        #pragma unroll
        for (int ks2 = 0; ks2 < 2; ++ks2) {
            int q = ks2 * 4 + l4;
            bf16x8 a[2], bb[4];
            #pragma unroll
            for (int fm = 0; fm < 2; ++fm) {
                int ar = wm + fm * 16 + l15;
                a[fm] = *(const bf16x8*)&As[ar * 64 + ((q ^ (ar & 7)) << 3)];
            }
            #pragma unroll
            for (int fn = 0; fn < 4; ++fn) {
                int br = wn + fn * 16 + l15;
                bb[fn] = *(const bf16x8*)&Bs[br * 64 + ((q ^ (br & 7)) << 3)];
            }
            #pragma unroll
            for (int fm = 0; fm < 2; ++fm)
                #pragma unroll
                for (int fn = 0; fn < 4; ++fn)
                    acc[fm][fn] = __builtin_amdgcn_mfma_f32_16x16x32_bf16(a[fm], bb[fn], acc[fm][fn], 0, 0, 0);
        }
        __syncthreads();
    }
    float* zp = zpart + (size_t)ksb * B * H4;
    #pragma unroll
    for (int fm = 0; fm < 2; ++fm)
        #pragma unroll
        for (int j = 0; j < 4; ++j) {
            int m = rowbase + wm + fm * 16 + l4 * 4 + j;
            #pragma unroll
            for (int fn = 0; fn < 4; ++fn)
                zp[(size_t)m * H4 + nbase + wn + fn * 16 + l15] = acc[fm][fn][j];
        }
}

// ---------- fused cell + attention. grid (B, 2), 256 thr ----------
// Cell (t_next>0) computed redundantly by both halves from prev-launch state
// (cb_cur never written this launch -> no race); half 0 writes outputs.
// Context einsum split: half owns 128 uint-columns (256 features).
__global__ __launch_bounds__(256) void k_step_sep(
    const float* __restrict__ zpart, const float* __restrict__ bias,
    const float* __restrict__ cb_cur, float* __restrict__ cb_nxt,
    unsigned short* __restrict__ Abuf,
    const unsigned short* __restrict__ Xb, const float* __restrict__ fscore,
    const float* __restrict__ w_a_h,
    float* __restrict__ out_h, float* __restrict__ out_m, float* __restrict__ out_a,
    int t_next) {
    __shared__ float red[12];
    __shared__ float sal[200];
    __shared__ float sp2[2][128][2];
    int b = blockIdx.x, half = blockIdx.y, tid = threadIdx.x;
    int lane = tid & 63, wid = tid >> 6;
    int n0 = tid * 2;
    float hp;
    if (t_next > 0) {
        float2 z[4];
        #pragma unroll
        for (int g = 0; g < 4; ++g) z[g] = *(const float2*)(bias + g * H + n0);
        #pragma unroll
        for (int ks = 0; ks < KS; ++ks) {
            const float* zp = zpart + ((size_t)ks * B + b) * H4;
            #pragma unroll
            for (int g = 0; g < 4; ++g) {
                float2 v = *(const float2*)(zp + g * H + n0);
                z[g].x += v.x; z[g].y += v.y;
            }
        }
        float2 cv = *(const float2*)(cb_cur + (size_t)b * H + n0);
        float cnx = sigf(z[1].x) * cv.x + sigf(z[0].x) * tanhf(z[2].x);
        float cny = sigf(z[1].y) * cv.y + sigf(z[0].y) * tanhf(z[2].y);
        float hnx = sigf(z[3].x) * tanhf(cnx);
        float hny = sigf(z[3].y) * tanhf(cny);
        if (half == 0) {
            int tp = t_next - 1;
            *(float2*)(cb_nxt + (size_t)b * H + n0) = make_float2(cnx, cny);
            *(float2*)(out_m + ((size_t)tp * B + b) * H + n0) = make_float2(cnx, cny);
            *(float2*)(out_h + ((size_t)b * T + tp) * H + n0) = make_float2(hnx, hny);
            ushort2 hu; hu.x = f2bf(hnx); hu.y = f2bf(hny);
            *(ushort2*)(Abuf + (size_t)b * 1024 + 512 + n0) = hu;
        }
        hp = hnx * w_a_h[n0] + hny * w_a_h[n0 + 1];
    } else {
        ushort2 hu = *(const ushort2*)(Abuf + (size_t)b * 1024 + 512 + n0);
        hp = bf2f(hu.x) * w_a_h[n0] + bf2f(hu.y) * w_a_h[n0 + 1];
    }
    if (t_next >= T) return;

    float s = wred_sum(hp);
    if (lane == 0) red[wid] = s;
    __syncthreads();
    float hs = red[0] + red[1] + red[2] + red[3];
    float scv = (tid < L) ? tanhf(hs + fscore[b * L + tid]) : -3.0e38f;
    float m = wred_max(scv);
    if (lane == 0) red[4 + wid] = m;
    __syncthreads();
    float mx = fmaxf(fmaxf(red[4], red[5]), fmaxf(red[6], red[7]));
    float ex = (tid < L) ? expf(scv - mx) : 0.f;
    float es = wred_sum(ex);
    if (lane == 0) red[8 + wid] = es;
    __syncthreads();
    float denom = red[8] + red[9] + red[10] + red[11];
    float al = ex / denom;
    if (tid < L) {
        sal[tid] = al;
        if (half == 0) out_a[((size_t)b * T + t_next) * L + tid] = al;
    }
    __syncthreads();

    // context: this half owns uint cols half*128 + (tid&127); l split in 2x98
    int fi = tid & 127, lg = tid >> 7;
    const unsigned* xb32 = (const unsigned*)(Xb + (size_t)b * L * F2) + half * 128 + fi;
    int l0 = lg * 98;
    float a0 = 0.f, a1 = 0.f;
    for (int sblk = 0; sblk < 98; sblk += 14) {
        unsigned u[14];
        #pragma unroll
        for (int j = 0; j < 14; ++j) u[j] = xb32[(size_t)(l0 + sblk + j) * 256];
        #pragma unroll
        for (int j = 0; j < 14; ++j) {
            float w = sal[l0 + sblk + j];
            a0 += bf2f((unsigned short)(u[j] & 0xFFFF)) * w;
            a1 += bf2f((unsigned short)(u[j] >> 16)) * w;
        }
    }
    sp2[lg][fi][0] = a0; sp2[lg][fi][1] = a1;
    __syncthreads();
    if (tid < 128) {
        ushort2 cu;
        cu.x = f2bf(sp2[0][tid][0] + sp2[1][tid][0]);
        cu.y = f2bf(sp2[0][tid][1] + sp2[1][tid][1]);
        *(ushort2*)(Abuf + (size_t)b * 1024 + (half * 128 + tid) * 2) = cu;
    }
}

extern "C" void kernel_launch(void* const* d_in, const int* in_sizes, int n_in,
                              void* d_out, int out_size, void* d_ws, size_t ws_size,
                              hipStream_t stream) {
    (void)in_sizes; (void)n_in; (void)out_size; (void)ws_size;
    const float* X     = (const float*)d_in[0];
    const float* word  = (const float*)d_in[1];
    const float* w_h   = (const float*)d_in[2];
    const float* b_h   = (const float*)d_in[3];
    const float* w_c   = (const float*)d_in[4];
    const float* b_c   = (const float*)d_in[5];
    const float* w_a_h = (const float*)d_in[6];
    const float* w_a   = (const float*)d_in[7];
    const float* b_a   = (const float*)d_in[8];
    const float* k_w   = (const float*)d_in[9];
    const float* r_w   = (const float*)d_in[10];
    const float* bias  = (const float*)d_in[11];

    float* out_h = (float*)d_out;
    float* out_m = out_h + (size_t)B * T * H;
    float* out_a = out_m + (size_t)T * B * H;

    // ws layout — total 39,290,880 bytes (== proven round-3 footprint)
    char* p = (char*)d_ws;
    unsigned short* Xb    = (unsigned short*)p; p += (size_t)B * L * F2 * 2;
    unsigned short* WcatT = (unsigned short*)p; p += (size_t)H4 * KCAT * 2;
    unsigned short* wiT   = (unsigned short*)p; p += (size_t)1024 * 512 * 2;
    unsigned short* wordb = (unsigned short*)p; p += (size_t)B * T * D * 2;
    unsigned short* fmb   = (unsigned short*)p; p += (size_t)B * F2 * 2;
    unsigned short* Abuf  = (unsigned short*)p; p += (size_t)B * 1024 * 2;
    float* fscore = (float*)p; p += (size_t)B * L * 4;
    float* cb0    = (float*)p; p += (size_t)B * H * 4;
    float* cb1    = (float*)p; p += (size_t)B * H * 4;
    float* zpart  = (float*)p; p += (size_t)KS * B * H4 * 4;
    // fmpart (B*7*512 fp32 = 1.84 MB) aliases zpart (4.19 MB); lifetimes disjoint
    float* fmpart = zpart;

    k_prep2<<<dim3(B, 7), 256, 0, stream>>>(X, w_a, b_a, Xb, fscore, fmpart);
    k_mred<<<B, 256, 0, stream>>>(fmpart, fmb);
    k_castw<<<512, 256, 0, stream>>>(word, wordb);
    k_trW<<<dim3(16, 32, 3), 256, 0, stream>>>(k_w, r_w, WcatT);
    k_trI<<<dim3(16, 8, 2), 256, 0, stream>>>(w_h, w_c, wiT);
    k_init_gemm<<<8, 256, 0, stream>>>(fmb, wiT, b_h, b_c, Abuf, cb0);

    // c_t lives in cb[t&1]; init wrote cb0 (= c_0)
    float* cb[2] = {cb0, cb1};
    k_step_sep<<<dim3(B, 2), 256, 0, stream>>>(zpart, bias, cb0, cb1, Abuf, Xb,
                                               fscore, w_a_h, out_h, out_m, out_a, 0);
    for (int t = 0; t < T; ++t) {
        k_gemm_sep<<<128, 256, 0, stream>>>(Abuf, wordb, WcatT, zpart, t);
        k_step_sep<<<dim3(B, 2), 256, 0, stream>>>(zpart, bias, cb[t & 1], cb[(t + 1) & 1],
                                                   Abuf, Xb, fscore, w_a_h,
                                                   out_h, out_m, out_a, t + 1);
    }
}